// Round 2
// baseline (634.097 us; speedup 1.0000x reference)
//
#include <hip/hip_runtime.h>

// Problem constants (from setup_inputs): x[16,64,4096], emb[1024,64]
constexpr int B = 16, D = 64, T = 4096, E = 1024;
constexpr int NROW = B * T;            // 65536 rows of dim D
constexpr float DECAYF = 0.99f;
constexpr float OMDF   = 0.01f;        // 1 - decay
constexpr float EPSF   = 1e-5f;

constexpr int TW = 64;                 // codewords per LDS tile
constexpr int NT = E / TW;             // 16 tiles

// ws layout (floats): e2[1024] | counts[1024] | embed_sum[65536] | norm[1024]
// d_out layout (floats, ref return order):
//   embed_idx [B,T,D]  @0 | qx [B,D,T] @4194304 | idx [B,T] @8388608 |
//   new_embedding [E,D] @8454144 | new_ema_size [E] @8519680 | new_ema_w [D,E] @8520704

__device__ inline void gl_lds16(const float* g, float* l) {
  __builtin_amdgcn_global_load_lds((const __attribute__((address_space(1))) void*)g,
                                   (__attribute__((address_space(3))) void*)l, 16, 0, 0);
}
__device__ inline void gl_lds4(const float* g, float* l) {
  __builtin_amdgcn_global_load_lds((const __attribute__((address_space(1))) void*)g,
                                   (__attribute__((address_space(3))) void*)l, 4, 0, 0);
}

// ---- prep: e2[e] = numpy-pairwise sum of emb[e,:]^2 ; zero counts/embed_sum ----
__global__ __launch_bounds__(256) void prep_kernel(const float* __restrict__ emb,
                                                   float* __restrict__ ws) {
  int tid = blockIdx.x * 256 + threadIdx.x;
  if (tid < E) {
    #pragma clang fp contract(off)
    const float* ep = emb + tid * D;
    float r[8];
    #pragma unroll
    for (int j = 0; j < 8; ++j) { float v = ep[j]; r[j] = v * v; }
    #pragma unroll
    for (int k = 1; k < 8; ++k) {
      #pragma unroll
      for (int j = 0; j < 8; ++j) { float v = ep[8 * k + j]; r[j] += v * v; }
    }
    ws[tid] = ((r[0] + r[1]) + (r[2] + r[3])) + ((r[4] + r[5]) + (r[6] + r[7]));
  } else if (tid < 1024 + 1024 + 65536) {
    ws[tid] = 0.0f;  // counts + embed_sum
  }
}

// ---- assign: 128 threads = 2 waves = 128 rows/block; each wave scans all E
//      from LDS-staged codebook tiles (broadcast ds_read_b128). ----
__global__ __launch_bounds__(128) void assign_kernel(
    const float* __restrict__ x, const float* __restrict__ emb,
    const float* __restrict__ e2s, float* __restrict__ counts,
    float* __restrict__ embed_sum, float* __restrict__ out_embed_idx,
    float* __restrict__ out_qx, float* __restrict__ out_idx) {
  __shared__ alignas(16) float s_cw[2][TW * D + 32];  // +32 pad: prefetch overrun lands here
  __shared__ float s_e2[2][TW];

  const int tid = threadIdx.x;                 // 0..127
  const int row = blockIdx.x * 128 + tid;      // one row per thread
  const int b = row >> 12;                     // T = 4096
  const int tt = row & (T - 1);
  const float* xrow = x + (size_t)b * D * T + tt;

  float xv[64];
  #pragma unroll
  for (int d = 0; d < D; ++d) xv[d] = xrow[(size_t)d * T];  // coalesced per d

  // x2: replicate numpy pairwise sum (n=64: 8 strided accumulators)
  float x2;
  {
    #pragma clang fp contract(off)
    float r[8];
    #pragma unroll
    for (int j = 0; j < 8; ++j) r[j] = xv[j] * xv[j];
    #pragma unroll
    for (int k = 1; k < 8; ++k) {
      #pragma unroll
      for (int j = 0; j < 8; ++j) r[j] += xv[8 * k + j] * xv[8 * k + j];
    }
    x2 = ((r[0] + r[1]) + (r[2] + r[3])) + ((r[4] + r[5]) + (r[6] + r[7]));
  }

  // stage tile -> LDS buffer bsel (async, wave-uniform base + lane*16 pattern)
  auto stage = [&](int tile, int bsel) {
    const float* src = emb + (size_t)tile * (TW * D);
    #pragma unroll
    for (int i = 0; i < 8; ++i) {
      int off = (i * 128 + tid) * 4;           // float index, 16B per thread
      gl_lds16(src + off, &s_cw[bsel][off]);
    }
    if (tid < TW) gl_lds4(e2s + tile * TW + tid, &s_e2[bsel][tid]);
  };

  stage(0, 0);

  float best = 3.4e38f;
  int bidx = 0;

  for (int tl = 0; tl < NT; ++tl) {
    __syncthreads();                            // tile tl staged; buf (tl+1)&1 free
    if (tl + 1 < NT) stage(tl + 1, (tl + 1) & 1);

    const float4* cv = (const float4*)s_cw[tl & 1];
    const float* e2t = s_e2[tl & 1];

    float4 ca[16], cb[16];
    #pragma unroll
    for (int k = 0; k < 16; ++k) ca[k] = cv[k];

    #pragma unroll 4
    for (int ei = 0; ei < TW; ei += 2) {
      // prefetch codeword ei+1 while scoring ei
      #pragma unroll
      for (int k = 0; k < 16; ++k) cb[k] = cv[(ei + 1) * 16 + k];
      {
        float d0 = 0.f, d1 = 0.f, d2 = 0.f, d3 = 0.f;
        #pragma unroll
        for (int k = 0; k < 16; ++k) {
          d0 = __builtin_fmaf(xv[4 * k + 0], ca[k].x, d0);
          d1 = __builtin_fmaf(xv[4 * k + 1], ca[k].y, d1);
          d2 = __builtin_fmaf(xv[4 * k + 2], ca[k].z, d2);
          d3 = __builtin_fmaf(xv[4 * k + 3], ca[k].w, d3);
        }
        float dot = (d0 + d1) + (d2 + d3);
        float sc = __builtin_fmaf(-2.0f, dot, e2t[ei]);
        float q = sc + x2;
        int e = tl * TW + ei;
        if (q < best) { best = q; bidx = e; }
      }
      // prefetch codeword ei+2 (overruns into pad at ei=62) while scoring ei+1
      #pragma unroll
      for (int k = 0; k < 16; ++k) ca[k] = cv[(ei + 2) * 16 + k];
      {
        float d0 = 0.f, d1 = 0.f, d2 = 0.f, d3 = 0.f;
        #pragma unroll
        for (int k = 0; k < 16; ++k) {
          d0 = __builtin_fmaf(xv[4 * k + 0], cb[k].x, d0);
          d1 = __builtin_fmaf(xv[4 * k + 1], cb[k].y, d1);
          d2 = __builtin_fmaf(xv[4 * k + 2], cb[k].z, d2);
          d3 = __builtin_fmaf(xv[4 * k + 3], cb[k].w, d3);
        }
        float dot = (d0 + d1) + (d2 + d3);
        float sc = __builtin_fmaf(-2.0f, dot, e2t[ei + 1]);
        float q = sc + x2;
        int e = tl * TW + ei + 1;
        if (q < best) { best = q; bidx = e; }
      }
    }
  }

  // ---- epilogue: this thread owns its row completely ----
  out_idx[row] = (float)bidx;
  atomicAdd(&counts[bidx], 1.0f);

  const float4* eb = (const float4*)(emb + (size_t)bidx * D);
  float* qx_base = out_qx + (size_t)b * D * T + tt;
  float4* ei_base = (float4*)(out_embed_idx + (size_t)row * D);

  #pragma unroll
  for (int k = 0; k < 16; ++k) {
    float4 ev = eb[k];                    // gather (per-lane bidx), L2-hot
    ei_base[k] = ev;
    {
      const int d = 4 * k + 0; float xd = xv[d];
      qx_base[(size_t)d * T] = xd + (ev.x - xd);
      atomicAdd(&embed_sum[d * E + bidx], xd);
    }
    {
      const int d = 4 * k + 1; float xd = xv[d];
      qx_base[(size_t)d * T] = xd + (ev.y - xd);
      atomicAdd(&embed_sum[d * E + bidx], xd);
    }
    {
      const int d = 4 * k + 2; float xd = xv[d];
      qx_base[(size_t)d * T] = xd + (ev.z - xd);
      atomicAdd(&embed_sum[d * E + bidx], xd);
    }
    {
      const int d = 4 * k + 3; float xd = xv[d];
      qx_base[(size_t)d * T] = xd + (ev.w - xd);
      atomicAdd(&embed_sum[d * E + bidx], xd);
    }
  }
}

// ---- finalize_a: ema_size update + normalization (1 block of 1024) ----
__global__ __launch_bounds__(1024) void finalize_a(
    const float* __restrict__ ema_size, const float* __restrict__ counts,
    float* __restrict__ norm, float* __restrict__ out_ema_size) {
  const int e = threadIdx.x;
  float ns = DECAYF * ema_size[e] + OMDF * counts[e];
  __shared__ float red[1024];
  red[e] = ns;
  __syncthreads();
  for (int s = 512; s > 0; s >>= 1) {
    if (e < s) red[e] += red[e + s];
    __syncthreads();
  }
  float n = red[0];
  float v = ((ns + EPSF) / (n + (float)E * EPSF)) * n;
  out_ema_size[e] = v;
  norm[e] = v;
}

// ---- finalize_b: new_ema_w + new_embedding ----
__global__ __launch_bounds__(256) void finalize_b(
    const float* __restrict__ ema_w, const float* __restrict__ embed_sum,
    const float* __restrict__ norm, float* __restrict__ out_embedding,
    float* __restrict__ out_ema_w) {
  int i = blockIdx.x * 256 + threadIdx.x;  // i = d*E + e
  int d = i >> 10;
  int e = i & (E - 1);
  float w = DECAYF * ema_w[i] + OMDF * embed_sum[i];
  out_ema_w[i] = w;
  out_embedding[e * D + d] = w / norm[e];
}

extern "C" void kernel_launch(void* const* d_in, const int* in_sizes, int n_in,
                              void* d_out, int out_size, void* d_ws, size_t ws_size,
                              hipStream_t stream) {
  const float* x        = (const float*)d_in[0];
  const float* emb      = (const float*)d_in[1];
  const float* ema_size = (const float*)d_in[2];
  const float* ema_w    = (const float*)d_in[3];

  float* out = (float*)d_out;
  float* o_embed_idx = out;                // [B,T,D]
  float* o_qx        = out + 4194304;      // [B,D,T]
  float* o_idx       = out + 8388608;      // [B,T]
  float* o_embedding = out + 8454144;      // [E,D]
  float* o_ema_size  = out + 8519680;      // [E]
  float* o_ema_w     = out + 8520704;      // [D,E]

  float* ws      = (float*)d_ws;
  float* w_e2    = ws;             // 1024
  float* w_counts= ws + 1024;      // 1024
  float* w_esum  = ws + 2048;      // 65536
  float* w_norm  = ws + 67584;     // 1024

  prep_kernel<<<264, 256, 0, stream>>>(emb, ws);
  assign_kernel<<<NROW / 128, 128, 0, stream>>>(x, emb, w_e2, w_counts, w_esum,
                                                o_embed_idx, o_qx, o_idx);
  finalize_a<<<1, 1024, 0, stream>>>(ema_size, w_counts, w_norm, o_ema_size);
  finalize_b<<<E * D / 256, 256, 0, stream>>>(ema_w, w_esum, w_norm,
                                              o_embedding, o_ema_w);
}